// Round 2
// baseline (323.189 us; speedup 1.0000x reference)
//
#include <hip/hip_runtime.h>
#include <hip/hip_bf16.h>

constexpr int D        = 100;
constexpr int K        = 20;
constexpr int N_USER   = 50000;
constexpr int N_ENTITY = 60000;
constexpr int N_NEWS   = 20000;
constexpr int NNZ      = 500000;

// ---------------------------------------------------------------------------
// Unweighted neighbor-sum aggregation (softmax over size-1 axis == 1.0):
//   out[row,:] = sum_k table[idx[row,k],:] + base[row,:]
// One wave per row; neighbor indices broadcast via __shfl.
// ---------------------------------------------------------------------------
__global__ __launch_bounds__(256) void sumagg_kernel(
    const float* __restrict__ table,
    const int*   __restrict__ idx_mat,   // n x K
    const float* __restrict__ base,
    float*       __restrict__ out,
    int n)
{
    int wave = (int)((blockIdx.x * blockDim.x + threadIdx.x) >> 6);
    int lane = threadIdx.x & 63;
    if (wave >= n) return;

    int idxv = (lane < K) ? idx_mat[(size_t)wave * K + lane] : 0;

    float acc0 = 0.f, acc1 = 0.f;
    int l2 = lane + 64;
    #pragma unroll
    for (int k = 0; k < K; ++k) {
        int ei = __shfl(idxv, k);
        const float* r = table + (size_t)ei * D;
        acc0 += r[lane];
        if (l2 < D) acc1 += r[l2];
    }
    const float* b = base + (size_t)wave * D;
    float*       o = out  + (size_t)wave * D;
    o[lane] = acc0 + b[lane];
    if (l2 < D) o[l2] = acc1 + b[l2];
}

// ---------------------------------------------------------------------------
// user_agg init: copy user_emb (float4-vectorized)
// ---------------------------------------------------------------------------
__global__ __launch_bounds__(256) void copy_kernel(
    const float4* __restrict__ src, float4* __restrict__ dst, int n4)
{
    int i = (int)(blockIdx.x * blockDim.x + threadIdx.x);
    if (i < n4) dst[i] = src[i];
}

// ---------------------------------------------------------------------------
// Scatter: user[rows[j],:] += vals[j] * node[cols[j],:]   one wave per nnz
// ---------------------------------------------------------------------------
__global__ __launch_bounds__(256) void scatter_kernel(
    const float* __restrict__ vals, const int* __restrict__ rows,
    const int* __restrict__ cols, const float* __restrict__ node,
    float* __restrict__ user, int nnz)
{
    int j    = (int)((blockIdx.x * blockDim.x + threadIdx.x) >> 6);
    int lane = threadIdx.x & 63;
    if (j >= nnz) return;
    int   r = rows[j];
    int   c = cols[j];
    float v = vals[j];
    const float* src = node + (size_t)c * D;
    float*       dst = user + (size_t)r * D;
    unsafeAtomicAdd(&dst[lane], v * src[lane]);
    int l2 = lane + 64;
    if (l2 < D) unsafeAtomicAdd(&dst[l2], v * src[l2]);
}

// ---------------------------------------------------------------------------
extern "C" void kernel_launch(void* const* d_in, const int* in_sizes, int n_in,
                              void* d_out, int out_size, void* d_ws, size_t ws_size,
                              hipStream_t stream)
{
    const float* user_emb = (const float*)d_in[0];
    const float* all_emb  = (const float*)d_in[1];
    const float* ent_emb  = (const float*)d_in[2];
    // d_in[3..7]: relation_emb, W_news, b_news, W_ent, b_ent — dead inputs
    // (softmax over a size-1 axis is identically 1.0 in the reference).
    const float* vals     = (const float*)d_in[8];
    const int*   news_ent = (const int*)d_in[9];
    // d_in[10] = news_relations : dead
    const int*   ngh_ent  = (const int*)d_in[11];
    // d_in[12] = neigh_relations : dead
    const int*   irows    = (const int*)d_in[13];
    const int*   icols    = (const int*)d_in[14];

    float* node = (float*)d_out;                                   // 80000 x 100
    float* user = (float*)d_out + (size_t)(N_NEWS + N_ENTITY) * D; // 50000 x 100

    // user_agg = user_emb (stream-ordered before scatter)
    int n4 = N_USER * D / 4;
    copy_kernel<<<(n4 + 255) / 256, 256, 0, stream>>>(
        (const float4*)user_emb, (float4*)user, n4);

    // node_emb rows (4 waves per 256-thread block)
    sumagg_kernel<<<(N_NEWS + 3) / 4, 256, 0, stream>>>(
        ent_emb, news_ent, all_emb, node, N_NEWS);
    sumagg_kernel<<<(N_ENTITY + 3) / 4, 256, 0, stream>>>(
        all_emb, ngh_ent, all_emb, node + (size_t)N_NEWS * D, N_ENTITY);

    // user_agg += segment_sum(vals * node_emb[cols] -> rows)
    scatter_kernel<<<(NNZ + 3) / 4, 256, 0, stream>>>(
        vals, irows, icols, node, user, NNZ);
}

// Round 3
// 205.566 us; speedup vs baseline: 1.5722x; 1.5722x over previous
//
#include <hip/hip_runtime.h>
#include <hip/hip_bf16.h>

constexpr int D        = 100;
constexpr int K        = 20;
constexpr int N_USER   = 50000;
constexpr int N_ENTITY = 60000;
constexpr int N_NEWS   = 20000;
constexpr int NNZ      = 500000;
constexpr int CAP      = 32;     // bucket capacity per user (avg degree = 10)

// ---------------------------------------------------------------------------
// Unweighted neighbor-sum aggregation (softmax over size-1 axis == 1.0):
//   out[row,:] = sum_k table[idx[row,k],:] + base[row,:]
// One wave per row; neighbor indices broadcast via __shfl.
// ---------------------------------------------------------------------------
__global__ __launch_bounds__(256) void sumagg_kernel(
    const float* __restrict__ table,
    const int*   __restrict__ idx_mat,   // n x K
    const float* __restrict__ base,
    float*       __restrict__ out,
    int n)
{
    int wave = (int)((blockIdx.x * blockDim.x + threadIdx.x) >> 6);
    int lane = threadIdx.x & 63;
    if (wave >= n) return;

    int idxv = (lane < K) ? idx_mat[(size_t)wave * K + lane] : 0;

    float acc0 = 0.f, acc1 = 0.f;
    int l2 = lane + 64;
    #pragma unroll
    for (int k = 0; k < K; ++k) {
        int ei = __shfl(idxv, k);
        const float* r = table + (size_t)ei * D;
        acc0 += r[lane];
        if (l2 < D) acc1 += r[l2];
    }
    const float* b = base + (size_t)wave * D;
    float*       o = out  + (size_t)wave * D;
    o[lane] = acc0 + b[lane];
    if (l2 < D) o[l2] = acc1 + b[l2];
}

// ---------------------------------------------------------------------------
// Bucket build: counts + per-entry position + bucket fill (entry indices)
// ---------------------------------------------------------------------------
__global__ __launch_bounds__(256) void zero_counts_kernel(int* __restrict__ counts, int n)
{
    int i = (int)(blockIdx.x * blockDim.x + threadIdx.x);
    if (i < n) counts[i] = 0;
}

__global__ __launch_bounds__(256) void hist_fill_kernel(
    const int* __restrict__ rows,
    int* __restrict__ counts, int* __restrict__ pos_arr, int* __restrict__ buckets,
    int nnz)
{
    int j = (int)(blockIdx.x * blockDim.x + threadIdx.x);
    if (j >= nnz) return;
    int r   = rows[j];
    int pos = atomicAdd(&counts[r], 1);
    pos_arr[j] = pos;
    if (pos < CAP) buckets[(size_t)r * CAP + pos] = j;
}

// ---------------------------------------------------------------------------
// Per-user aggregate (gather form of the segment-sum):
//   user[u,:] = user_emb[u,:] + sum_{j in bucket(u)} vals[j]*node[cols[j],:]
// One wave per user; entry metadata broadcast via __shfl.
// ---------------------------------------------------------------------------
__global__ __launch_bounds__(256) void user_agg_kernel(
    const int*   __restrict__ counts, const int* __restrict__ buckets,
    const int*   __restrict__ cols,   const float* __restrict__ vals,
    const float* __restrict__ node,   const float* __restrict__ user_emb,
    float*       __restrict__ user)
{
    int u    = (int)((blockIdx.x * blockDim.x + threadIdx.x) >> 6);
    int lane = threadIdx.x & 63;
    if (u >= N_USER) return;

    int c = counts[u];
    if (c > CAP) c = CAP;

    int   j    = (lane < c) ? buckets[(size_t)u * CAP + lane] : 0;
    int   colv = (lane < c) ? cols[j] : 0;
    float valv = (lane < c) ? vals[j] : 0.f;

    float acc0 = 0.f, acc1 = 0.f;
    int l2 = lane + 64;
    for (int e = 0; e < c; ++e) {
        int   col = __shfl(colv, e);
        float v   = __shfl(valv, e);
        const float* r = node + (size_t)col * D;
        acc0 += v * r[lane];
        if (l2 < D) acc1 += v * r[l2];
    }
    const float* ue = user_emb + (size_t)u * D;
    float*       o  = user     + (size_t)u * D;
    o[lane] = acc0 + ue[lane];
    if (l2 < D) o[l2] = acc1 + ue[l2];
}

// ---------------------------------------------------------------------------
// Overflow cleanup: entries whose claimed position >= CAP (should be none for
// this input; kept for unconditional correctness). Runs AFTER user_agg.
// ---------------------------------------------------------------------------
__global__ __launch_bounds__(256) void overflow_kernel(
    const int* __restrict__ pos_arr, const int* __restrict__ rows,
    const int* __restrict__ cols,    const float* __restrict__ vals,
    const float* __restrict__ node,  float* __restrict__ user, int nnz)
{
    int j = (int)(blockIdx.x * blockDim.x + threadIdx.x);
    if (j >= nnz || pos_arr[j] < CAP) return;
    int   r = rows[j];
    int   c = cols[j];
    float v = vals[j];
    const float* src = node + (size_t)c * D;
    float*       dst = user + (size_t)r * D;
    for (int d = 0; d < D; ++d) unsafeAtomicAdd(&dst[d], v * src[d]);
}

// ---------------------------------------------------------------------------
// Fallback path (only if workspace too small): copy + direct atomic scatter
// ---------------------------------------------------------------------------
__global__ __launch_bounds__(256) void copy_kernel(
    const float4* __restrict__ src, float4* __restrict__ dst, int n4)
{
    int i = (int)(blockIdx.x * blockDim.x + threadIdx.x);
    if (i < n4) dst[i] = src[i];
}

__global__ __launch_bounds__(256) void scatter_kernel(
    const float* __restrict__ vals, const int* __restrict__ rows,
    const int* __restrict__ cols, const float* __restrict__ node,
    float* __restrict__ user, int nnz)
{
    int j    = (int)((blockIdx.x * blockDim.x + threadIdx.x) >> 6);
    int lane = threadIdx.x & 63;
    if (j >= nnz) return;
    int   r = rows[j];
    int   c = cols[j];
    float v = vals[j];
    const float* src = node + (size_t)c * D;
    float*       dst = user + (size_t)r * D;
    unsafeAtomicAdd(&dst[lane], v * src[lane]);
    int l2 = lane + 64;
    if (l2 < D) unsafeAtomicAdd(&dst[l2], v * src[l2]);
}

// ---------------------------------------------------------------------------
extern "C" void kernel_launch(void* const* d_in, const int* in_sizes, int n_in,
                              void* d_out, int out_size, void* d_ws, size_t ws_size,
                              hipStream_t stream)
{
    const float* user_emb = (const float*)d_in[0];
    const float* all_emb  = (const float*)d_in[1];
    const float* ent_emb  = (const float*)d_in[2];
    // d_in[3..7]: relation_emb, W_news, b_news, W_ent, b_ent — dead inputs
    // (softmax over a size-1 axis is identically 1.0 in the reference).
    const float* vals     = (const float*)d_in[8];
    const int*   news_ent = (const int*)d_in[9];
    const int*   ngh_ent  = (const int*)d_in[11];
    const int*   irows    = (const int*)d_in[13];
    const int*   icols    = (const int*)d_in[14];

    float* node = (float*)d_out;                                   // 80000 x 100
    float* user = (float*)d_out + (size_t)(N_NEWS + N_ENTITY) * D; // 50000 x 100

    // node_emb rows (4 waves per 256-thread block)
    sumagg_kernel<<<(N_NEWS + 3) / 4, 256, 0, stream>>>(
        ent_emb, news_ent, all_emb, node, N_NEWS);
    sumagg_kernel<<<(N_ENTITY + 3) / 4, 256, 0, stream>>>(
        all_emb, ngh_ent, all_emb, node + (size_t)N_NEWS * D, N_ENTITY);

    // ---- segment-sum as gather via per-user buckets ----
    size_t need = ((size_t)N_USER + NNZ + (size_t)N_USER * CAP) * sizeof(int);
    if (ws_size >= need) {
        int* counts  = (int*)d_ws;             // N_USER
        int* pos_arr = counts + N_USER;        // NNZ
        int* buckets = pos_arr + NNZ;          // N_USER * CAP

        zero_counts_kernel<<<(N_USER + 255) / 256, 256, 0, stream>>>(counts, N_USER);
        hist_fill_kernel<<<(NNZ + 255) / 256, 256, 0, stream>>>(
            irows, counts, pos_arr, buckets, NNZ);
        user_agg_kernel<<<(N_USER + 3) / 4, 256, 0, stream>>>(
            counts, buckets, icols, vals, node, user_emb, user);
        overflow_kernel<<<(NNZ + 255) / 256, 256, 0, stream>>>(
            pos_arr, irows, icols, vals, node, user, NNZ);
    } else {
        // fallback: direct atomic scatter
        int n4 = N_USER * D / 4;
        copy_kernel<<<(n4 + 255) / 256, 256, 0, stream>>>(
            (const float4*)user_emb, (float4*)user, n4);
        scatter_kernel<<<(NNZ + 3) / 4, 256, 0, stream>>>(
            vals, irows, icols, node, user, NNZ);
    }
}

// Round 4
// 179.476 us; speedup vs baseline: 1.8007x; 1.1454x over previous
//
#include <hip/hip_runtime.h>
#include <hip/hip_bf16.h>

constexpr int D        = 100;
constexpr int K        = 20;
constexpr int N_USER   = 50000;
constexpr int N_ENTITY = 60000;
constexpr int N_NEWS   = 20000;
constexpr int NNZ      = 500000;
constexpr int CAP      = 32;     // bucket capacity per user (avg degree = 10)
constexpr int N_NODE   = N_NEWS + N_ENTITY;

// ---- bf16 helpers (bit-level, RNE) ----------------------------------------
static __device__ __forceinline__ unsigned short f2b(float x) {
    union { float f; unsigned int u; } c; c.f = x;
    unsigned int u = c.u;
    return (unsigned short)((u + 0x7FFFu + ((u >> 16) & 1u)) >> 16);
}
static __device__ __forceinline__ float b2f(unsigned short u) {
    union { unsigned int u; float f; } c; c.u = ((unsigned int)u) << 16; return c.f;
}

// ---------------------------------------------------------------------------
// f32 -> bf16 table conversion, float4 -> ushort4, 4 elems/thread
// ---------------------------------------------------------------------------
__global__ __launch_bounds__(256) void cvt_kernel(
    const float4* __restrict__ src, ushort4* __restrict__ dst, int n4)
{
    int i = (int)(blockIdx.x * blockDim.x + threadIdx.x);
    if (i >= n4) return;
    float4 v = src[i];
    ushort4 o;
    o.x = f2b(v.x); o.y = f2b(v.y); o.z = f2b(v.z); o.w = f2b(v.w);
    dst[i] = o;
}

// ---------------------------------------------------------------------------
// Merged neighbor-sum aggregation (softmax over size-1 axis == 1.0), bf16
// gather tables, f32 residual/base, writes f32 node + bf16 shadow node.
//   row < N_NEWS : table = bf16(entity_emb), idx = news_entities
//   else         : table = bf16(all_emb),    idx = neigh_entities
// One wave per row; 50 active lanes read ushort2 (2 elems) each.
// ---------------------------------------------------------------------------
__global__ __launch_bounds__(256) void sumagg_bf16_kernel(
    const unsigned short* __restrict__ entB,
    const unsigned short* __restrict__ allB,
    const int*   __restrict__ news_ent,
    const int*   __restrict__ ngh_ent,
    const float* __restrict__ all_emb,
    float*       __restrict__ node,
    unsigned short* __restrict__ nodeB)
{
    int row  = (int)((blockIdx.x * blockDim.x + threadIdx.x) >> 6);
    int lane = threadIdx.x & 63;
    if (row >= N_NODE) return;

    const unsigned short* table;
    const int* idxp;
    int brow;
    if (row < N_NEWS) { table = entB; idxp = news_ent + (size_t)row * K; brow = row; }
    else { int r = row - N_NEWS; table = allB; idxp = ngh_ent + (size_t)r * K; brow = r; }

    int idxv = (lane < K) ? idxp[lane] : 0;
    bool act = lane < D / 2;   // 50 lanes x 2 elems = 100
    float a0 = 0.f, a1 = 0.f;
    #pragma unroll
    for (int k = 0; k < K; ++k) {
        int ei = __shfl(idxv, k);
        if (act) {
            ushort2 t = *(const ushort2*)(table + (size_t)ei * D + lane * 2);
            a0 += b2f(t.x); a1 += b2f(t.y);
        }
    }
    if (act) {
        float2 b = *(const float2*)(all_emb + (size_t)brow * D + lane * 2);
        float o0 = a0 + b.x, o1 = a1 + b.y;
        *(float2*)(node + (size_t)row * D + lane * 2) = make_float2(o0, o1);
        ushort2 ob; ob.x = f2b(o0); ob.y = f2b(o1);
        *(ushort2*)(nodeB + (size_t)row * D + lane * 2) = ob;
    }
}

// ---------------------------------------------------------------------------
// Bucket build: counts + per-entry position + direct (col,val) bucket fill
// ---------------------------------------------------------------------------
__global__ __launch_bounds__(256) void zero_counts_kernel(int* __restrict__ counts, int n)
{
    int i = (int)(blockIdx.x * blockDim.x + threadIdx.x);
    if (i < n) counts[i] = 0;
}

__global__ __launch_bounds__(256) void hist_fill2_kernel(
    const int* __restrict__ rows, const int* __restrict__ cols,
    const float* __restrict__ vals,
    int* __restrict__ counts, int* __restrict__ pos_arr,
    int* __restrict__ bcol, float* __restrict__ bval, int nnz)
{
    int j = (int)(blockIdx.x * blockDim.x + threadIdx.x);
    if (j >= nnz) return;
    int r   = rows[j];
    int pos = atomicAdd(&counts[r], 1);
    pos_arr[j] = pos;
    if (pos < CAP) {
        bcol[(size_t)r * CAP + pos] = cols[j];
        bval[(size_t)r * CAP + pos] = vals[j];
    }
}

// ---------------------------------------------------------------------------
// Per-user aggregate, bf16 node gather:
//   user[u,:] = user_emb[u,:] + sum vals*nodeB[cols,:]
// ---------------------------------------------------------------------------
__global__ __launch_bounds__(256) void user_agg_bf16_kernel(
    const int* __restrict__ counts, const int* __restrict__ bcol,
    const float* __restrict__ bval, const unsigned short* __restrict__ nodeB,
    const float* __restrict__ user_emb, float* __restrict__ user)
{
    int u    = (int)((blockIdx.x * blockDim.x + threadIdx.x) >> 6);
    int lane = threadIdx.x & 63;
    if (u >= N_USER) return;

    int c = counts[u];
    if (c > CAP) c = CAP;
    int   colv = (lane < c) ? bcol[(size_t)u * CAP + lane] : 0;
    float valv = (lane < c) ? bval[(size_t)u * CAP + lane] : 0.f;

    bool act = lane < D / 2;
    float a0 = 0.f, a1 = 0.f;
    for (int e = 0; e < c; ++e) {
        int   col = __shfl(colv, e);
        float v   = __shfl(valv, e);
        if (act) {
            ushort2 t = *(const ushort2*)(nodeB + (size_t)col * D + lane * 2);
            a0 += v * b2f(t.x); a1 += v * b2f(t.y);
        }
    }
    if (act) {
        float2 ue = *(const float2*)(user_emb + (size_t)u * D + lane * 2);
        *(float2*)(user + (size_t)u * D + lane * 2) = make_float2(a0 + ue.x, a1 + ue.y);
    }
}

// ---------------------------------------------------------------------------
// Overflow cleanup (entries with pos >= CAP; none expected, kept for
// unconditional correctness). Uses f32 node. Runs AFTER user_agg.
// ---------------------------------------------------------------------------
__global__ __launch_bounds__(256) void overflow_kernel(
    const int* __restrict__ pos_arr, const int* __restrict__ rows,
    const int* __restrict__ cols,    const float* __restrict__ vals,
    const float* __restrict__ node,  float* __restrict__ user, int nnz)
{
    int j = (int)(blockIdx.x * blockDim.x + threadIdx.x);
    if (j >= nnz || pos_arr[j] < CAP) return;
    int   r = rows[j];
    int   c = cols[j];
    float v = vals[j];
    const float* src = node + (size_t)c * D;
    float*       dst = user + (size_t)r * D;
    for (int d = 0; d < D; ++d) unsafeAtomicAdd(&dst[d], v * src[d]);
}

// ---------------------------------------------------------------------------
// Fallback tier kernels (f32 path; used only if workspace is small)
// ---------------------------------------------------------------------------
__global__ __launch_bounds__(256) void sumagg_f32_kernel(
    const float* __restrict__ table, const int* __restrict__ idx_mat,
    const float* __restrict__ base, float* __restrict__ out, int n)
{
    int wave = (int)((blockIdx.x * blockDim.x + threadIdx.x) >> 6);
    int lane = threadIdx.x & 63;
    if (wave >= n) return;
    int idxv = (lane < K) ? idx_mat[(size_t)wave * K + lane] : 0;
    float acc0 = 0.f, acc1 = 0.f;
    int l2 = lane + 64;
    #pragma unroll
    for (int k = 0; k < K; ++k) {
        int ei = __shfl(idxv, k);
        const float* r = table + (size_t)ei * D;
        acc0 += r[lane];
        if (l2 < D) acc1 += r[l2];
    }
    const float* b = base + (size_t)wave * D;
    float*       o = out  + (size_t)wave * D;
    o[lane] = acc0 + b[lane];
    if (l2 < D) o[l2] = acc1 + b[l2];
}

__global__ __launch_bounds__(256) void copy_kernel(
    const float4* __restrict__ src, float4* __restrict__ dst, int n4)
{
    int i = (int)(blockIdx.x * blockDim.x + threadIdx.x);
    if (i < n4) dst[i] = src[i];
}

__global__ __launch_bounds__(256) void scatter_kernel(
    const float* __restrict__ vals, const int* __restrict__ rows,
    const int* __restrict__ cols, const float* __restrict__ node,
    float* __restrict__ user, int nnz)
{
    int j    = (int)((blockIdx.x * blockDim.x + threadIdx.x) >> 6);
    int lane = threadIdx.x & 63;
    if (j >= nnz) return;
    int   r = rows[j];
    int   c = cols[j];
    float v = vals[j];
    const float* src = node + (size_t)c * D;
    float*       dst = user + (size_t)r * D;
    unsafeAtomicAdd(&dst[lane], v * src[lane]);
    int l2 = lane + 64;
    if (l2 < D) unsafeAtomicAdd(&dst[l2], v * src[l2]);
}

__global__ __launch_bounds__(256) void user_agg_f32_kernel(
    const int* __restrict__ counts, const int* __restrict__ bcol,
    const float* __restrict__ bval, const float* __restrict__ node,
    const float* __restrict__ user_emb, float* __restrict__ user)
{
    int u    = (int)((blockIdx.x * blockDim.x + threadIdx.x) >> 6);
    int lane = threadIdx.x & 63;
    if (u >= N_USER) return;
    int c = counts[u];
    if (c > CAP) c = CAP;
    int   colv = (lane < c) ? bcol[(size_t)u * CAP + lane] : 0;
    float valv = (lane < c) ? bval[(size_t)u * CAP + lane] : 0.f;
    float a0 = 0.f, a1 = 0.f;
    int l2 = lane + 64;
    for (int e = 0; e < c; ++e) {
        int   col = __shfl(colv, e);
        float v   = __shfl(valv, e);
        const float* r = node + (size_t)col * D;
        a0 += v * r[lane];
        if (l2 < D) a1 += v * r[l2];
    }
    const float* ue = user_emb + (size_t)u * D;
    float*       o  = user     + (size_t)u * D;
    o[lane] = a0 + ue[lane];
    if (l2 < D) o[l2] = a1 + ue[l2];
}

// ---------------------------------------------------------------------------
extern "C" void kernel_launch(void* const* d_in, const int* in_sizes, int n_in,
                              void* d_out, int out_size, void* d_ws, size_t ws_size,
                              hipStream_t stream)
{
    const float* user_emb = (const float*)d_in[0];
    const float* all_emb  = (const float*)d_in[1];
    const float* ent_emb  = (const float*)d_in[2];
    // d_in[3..7]: relation_emb, W_news, b_news, W_ent, b_ent — dead inputs
    // (softmax over a size-1 axis is identically 1.0 in the reference).
    const float* vals     = (const float*)d_in[8];
    const int*   news_ent = (const int*)d_in[9];
    const int*   ngh_ent  = (const int*)d_in[11];
    const int*   irows    = (const int*)d_in[13];
    const int*   icols    = (const int*)d_in[14];

    float* node = (float*)d_out;                         // 80000 x 100
    float* user = (float*)d_out + (size_t)N_NODE * D;    // 50000 x 100

    // workspace layout (tier A)
    int*   counts  = (int*)d_ws;                          // N_USER
    int*   pos_arr = counts + N_USER;                     // NNZ
    int*   bcol    = pos_arr + NNZ;                       // N_USER*CAP
    float* bval    = (float*)(bcol + (size_t)N_USER * CAP);   // N_USER*CAP
    unsigned short* entB  = (unsigned short*)(bval + (size_t)N_USER * CAP); // N_ENTITY*D
    unsigned short* allB  = entB + (size_t)N_ENTITY * D;  // N_ENTITY*D
    unsigned short* nodeB = allB + (size_t)N_ENTITY * D;  // N_NODE*D

    size_t need_bucket = ((size_t)N_USER + NNZ + 2ull * N_USER * CAP) * 4ull;
    size_t need_full   = need_bucket +
                         ((size_t)N_ENTITY * D * 2 + (size_t)N_NODE * D) * 2ull;

    if (ws_size >= need_full) {
        // ---- tier A: bf16 gather tables ----
        int n4e = N_ENTITY * D / 4;
        cvt_kernel<<<(n4e + 255) / 256, 256, 0, stream>>>(
            (const float4*)ent_emb, (ushort4*)entB, n4e);
        cvt_kernel<<<(n4e + 255) / 256, 256, 0, stream>>>(
            (const float4*)all_emb, (ushort4*)allB, n4e);

        zero_counts_kernel<<<(N_USER + 255) / 256, 256, 0, stream>>>(counts, N_USER);
        hist_fill2_kernel<<<(NNZ + 255) / 256, 256, 0, stream>>>(
            irows, icols, vals, counts, pos_arr, bcol, bval, NNZ);

        sumagg_bf16_kernel<<<(N_NODE + 3) / 4, 256, 0, stream>>>(
            entB, allB, news_ent, ngh_ent, all_emb, node, nodeB);

        user_agg_bf16_kernel<<<(N_USER + 3) / 4, 256, 0, stream>>>(
            counts, bcol, bval, nodeB, user_emb, user);
        overflow_kernel<<<(NNZ + 255) / 256, 256, 0, stream>>>(
            pos_arr, irows, icols, vals, node, user, NNZ);
    } else if (ws_size >= need_bucket) {
        // ---- tier B: f32 bucket-gather (round-3 structure) ----
        sumagg_f32_kernel<<<(N_NEWS + 3) / 4, 256, 0, stream>>>(
            ent_emb, news_ent, all_emb, node, N_NEWS);
        sumagg_f32_kernel<<<(N_ENTITY + 3) / 4, 256, 0, stream>>>(
            all_emb, ngh_ent, all_emb, node + (size_t)N_NEWS * D, N_ENTITY);
        zero_counts_kernel<<<(N_USER + 255) / 256, 256, 0, stream>>>(counts, N_USER);
        hist_fill2_kernel<<<(NNZ + 255) / 256, 256, 0, stream>>>(
            irows, icols, vals, counts, pos_arr, bcol, bval, NNZ);
        user_agg_f32_kernel<<<(N_USER + 3) / 4, 256, 0, stream>>>(
            counts, bcol, bval, node, user_emb, user);
        overflow_kernel<<<(NNZ + 255) / 256, 256, 0, stream>>>(
            pos_arr, irows, icols, vals, node, user, NNZ);
    } else {
        // ---- tier C: atomic scatter ----
        sumagg_f32_kernel<<<(N_NEWS + 3) / 4, 256, 0, stream>>>(
            ent_emb, news_ent, all_emb, node, N_NEWS);
        sumagg_f32_kernel<<<(N_ENTITY + 3) / 4, 256, 0, stream>>>(
            all_emb, ngh_ent, all_emb, node + (size_t)N_NEWS * D, N_ENTITY);
        int n4 = N_USER * D / 4;
        copy_kernel<<<(n4 + 255) / 256, 256, 0, stream>>>(
            (const float4*)user_emb, (float4*)user, n4);
        scatter_kernel<<<(NNZ + 3) / 4, 256, 0, stream>>>(
            vals, irows, icols, node, user, NNZ);
    }
}